// Round 5
// baseline (469.124 us; speedup 1.0000x reference)
//
#include <hip/hip_runtime.h>
#include <math.h>

#define BB 512
#define SS 1024
#define KK 128
#define VV 512
#define NC 4      // s-chunks per batch
#define CH 256    // rows per chunk

static constexpr float INV_SCALE = 0.088388347648318447f; // 1/sqrt(128)

// ---------------- query kernel: q[b,k] = hidden[b] . Wq[k] + bq[k] -----------
__global__ __launch_bounds__(128) void q_kernel(
    const float* __restrict__ hidden, const float* __restrict__ Wq,
    const float* __restrict__ bq, float* __restrict__ qout)
{
    __shared__ __align__(16) float hid[VV];
    const int b = blockIdx.x, t = threadIdx.x;
    ((float4*)hid)[t] = ((const float4*)(hidden + (size_t)b * VV))[t];
    __syncthreads();
    const float4* w4 = (const float4*)(Wq + (size_t)t * VV);
    const float4* h4 = (const float4*)hid;
    float acc = 0.f;
    #pragma unroll 8
    for (int v = 0; v < VV / 4; ++v) {
        float4 a = w4[v], h = h4[v];
        acc += a.x * h.x + a.y * h.y + a.z * h.z + a.w * h.w;
    }
    qout[(size_t)b * KK + t] = acc + bq[t];
}

// ---------------- transpose the three MLP weights into ws --------------------
// Wg1 (512,1024)->wt1 (1024,512); Wg2 (512,512)->wt2; Wo (512,512)->wto
__global__ __launch_bounds__(256) void transpose3_kernel(
    const float* __restrict__ Wg1, const float* __restrict__ Wg2,
    const float* __restrict__ Wo,
    float* __restrict__ wt1, float* __restrict__ wt2, float* __restrict__ wto)
{
    __shared__ float tile[32][33];
    const int idx = blockIdx.x;
    const float* in; float* out; int C, R, tid;
    if (idx < 512)      { in = Wg1; out = wt1; R = 512; C = 1024; tid = idx; }
    else if (idx < 768) { in = Wg2; out = wt2; R = 512; C = 512;  tid = idx - 512; }
    else                { in = Wo;  out = wto; R = 512; C = 512;  tid = idx - 768; }
    const int tiles_x = C >> 5;
    const int bx = (tid % tiles_x) << 5;
    const int by = (tid / tiles_x) << 5;
    const int tx = threadIdx.x & 31, ty0 = threadIdx.x >> 5;
    #pragma unroll
    for (int i = 0; i < 32; i += 8)
        tile[ty0 + i][tx] = in[(size_t)(by + ty0 + i) * C + bx + tx];
    __syncthreads();
    #pragma unroll
    for (int i = 0; i < 32; i += 8)
        out[(size_t)(bx + ty0 + i) * R + by + tx] = tile[tx][ty0 + i];
}

// ---------------- attention chunk: scores+softmax partial+PV partial ---------
// grid = B*NC blocks, 256 threads. Emits (m, l, unnormalized acc) per chunk.
__global__ __launch_bounds__(256) void attn_chunk_kernel(
    const float* __restrict__ keys, const float* __restrict__ values,
    const float* __restrict__ keyv, const float* __restrict__ valv,
    const float* __restrict__ q,
    const int* __restrict__ write_ptr, const int* __restrict__ filled,
    float* __restrict__ ml, float* __restrict__ accp)
{
    __shared__ __align__(16) float qs[KK];
    __shared__ __align__(16) float p[CH];
    __shared__ __align__(16) float red[4];
    __shared__ __align__(16) float4 pvp[VV / 4];

    const int bc = blockIdx.x;
    const int b = bc >> 2;
    const int c = bc & 3;
    const int t = threadIdx.x;
    const int wave = t >> 6, lane = t & 63;

    int f = filled[b] + 1; if (f > SS) f = SS;
    const int sbeg = c * CH;
    int n = f - sbeg; if (n > CH) n = CH;

    float* mlrow = ml + ((size_t)b * NC + c) * 2;
    float* arow  = accp + ((size_t)b * NC + c) * VV;

    if (n <= 0) {
        if (t == 0) { mlrow[0] = -INFINITY; mlrow[1] = 0.f; }
        if (t < VV / 4) ((float4*)arow)[t] = make_float4(0.f, 0.f, 0.f, 0.f);
        return;
    }

    if (t < KK / 4) ((float4*)qs)[t] = ((const float4*)(q + (size_t)b * KK))[t];
    __syncthreads();

    // ---- scores: 32 lanes per row, 8 rows per sweep, unroll x4
    const int sub = lane & 31, rsel = lane >> 5;
    const int srow = wave * 2 + rsel;  // 0..7
    const float4 q4 = ((const float4*)qs)[sub];
    const float* kb = keys + ((size_t)b * SS + sbeg) * KK;
    const float* kw = keyv + (size_t)b * KK;
    const int wpl = write_ptr[b] - sbeg;

    const int nmain = n & ~31;
    for (int s0 = 0; s0 < nmain; s0 += 32) {
        float4 kv[4];
        #pragma unroll
        for (int u = 0; u < 4; ++u) {
            const int s = s0 + u * 8 + srow;
            const float* kr = (s == wpl) ? kw : (kb + (size_t)s * KK);
            kv[u] = ((const float4*)kr)[sub];
        }
        #pragma unroll
        for (int u = 0; u < 4; ++u) {
            float prt = kv[u].x * q4.x + kv[u].y * q4.y
                      + kv[u].z * q4.z + kv[u].w * q4.w;
            prt += __shfl_xor(prt, 16);
            prt += __shfl_xor(prt, 8);
            prt += __shfl_xor(prt, 4);
            prt += __shfl_xor(prt, 2);
            prt += __shfl_xor(prt, 1);
            if (sub == 0) p[s0 + u * 8 + srow] = prt * INV_SCALE;
        }
    }
    for (int s = nmain + srow; s < n; s += 8) {
        const float* kr = (s == wpl) ? kw : (kb + (size_t)s * KK);
        const float4 kv = ((const float4*)kr)[sub];
        float prt = kv.x * q4.x + kv.y * q4.y + kv.z * q4.z + kv.w * q4.w;
        prt += __shfl_xor(prt, 16);
        prt += __shfl_xor(prt, 8);
        prt += __shfl_xor(prt, 4);
        prt += __shfl_xor(prt, 2);
        prt += __shfl_xor(prt, 1);
        if (sub == 0) p[s] = prt * INV_SCALE;
    }
    __syncthreads();

    // ---- local softmax (store exp in p; emit m, l)
    float lmax = -INFINITY;
    for (int i = t; i < n; i += 256) lmax = fmaxf(lmax, p[i]);
    lmax = fmaxf(lmax, __shfl_xor(lmax, 32));
    lmax = fmaxf(lmax, __shfl_xor(lmax, 16));
    lmax = fmaxf(lmax, __shfl_xor(lmax, 8));
    lmax = fmaxf(lmax, __shfl_xor(lmax, 4));
    lmax = fmaxf(lmax, __shfl_xor(lmax, 2));
    lmax = fmaxf(lmax, __shfl_xor(lmax, 1));
    if (lane == 0) red[wave] = lmax;
    __syncthreads();
    const float m = fmaxf(fmaxf(red[0], red[1]), fmaxf(red[2], red[3]));
    float lsum = 0.f;
    for (int i = t; i < n; i += 256) {
        const float e = __expf(p[i] - m);
        p[i] = e;
        lsum += e;
    }
    lsum += __shfl_xor(lsum, 32);
    lsum += __shfl_xor(lsum, 16);
    lsum += __shfl_xor(lsum, 8);
    lsum += __shfl_xor(lsum, 4);
    lsum += __shfl_xor(lsum, 2);
    lsum += __shfl_xor(lsum, 1);
    __syncthreads();   // everyone done reading red (max) & writing p
    if (lane == 0) red[wave] = lsum;
    __syncthreads();
    const float l = red[0] + red[1] + red[2] + red[3];

    // ---- PV partial: acc[v] = sum_s exp(p) * values_w
    const int col4 = t & 127, stream = t >> 7;
    const float4* vb = (const float4*)(values + ((size_t)b * SS + sbeg) * VV);
    const float4* vw = (const float4*)(valv + (size_t)b * VV);
    float4 acc = make_float4(0.f, 0.f, 0.f, 0.f);
    const int nm2 = n & ~15;
    for (int s0 = 0; s0 < nm2; s0 += 16) {
        float4 v[8]; float ps[8];
        #pragma unroll
        for (int u = 0; u < 8; ++u) {
            const int s = s0 + u * 2 + stream;
            const float4* vr = (s == wpl) ? vw : (vb + (size_t)s * (VV / 4));
            v[u] = vr[col4];
            ps[u] = p[s];
        }
        #pragma unroll
        for (int u = 0; u < 8; ++u) {
            acc.x += ps[u] * v[u].x;
            acc.y += ps[u] * v[u].y;
            acc.z += ps[u] * v[u].z;
            acc.w += ps[u] * v[u].w;
        }
    }
    for (int s = nm2 + stream; s < n; s += 2) {
        const float4* vr = (s == wpl) ? vw : (vb + (size_t)s * (VV / 4));
        const float4 v = vr[col4];
        const float psv = p[s];
        acc.x += psv * v.x;
        acc.y += psv * v.y;
        acc.z += psv * v.z;
        acc.w += psv * v.w;
    }
    if (stream == 1) pvp[col4] = acc;
    __syncthreads();
    if (stream == 0) {
        const float4 o = pvp[col4];
        ((float4*)arow)[col4] = make_float4(acc.x + o.x, acc.y + o.y,
                                            acc.z + o.z, acc.w + o.w);
    }
    if (t == 0) { mlrow[0] = m; mlrow[1] = l; }
}

// ---------------- fused combine + gate MLP (transposed weights) --------------
// TBM=4 batches/block, 512 threads: thread = (bl = t>>7, quad = t&127),
// owns outputs j = 4*quad..4*quad+3 for batch bl. Weight loads coalesced.
#define TBM 4
__global__ __launch_bounds__(512) void mlp_kernel(
    const float* __restrict__ hidden,
    const float* __restrict__ ml, const float* __restrict__ accp,
    const float* __restrict__ wt1, const float* __restrict__ bg1, // (2V,V)
    const float* __restrict__ wt2, const float* __restrict__ bg2, // (V,V)
    const float* __restrict__ wto, const float* __restrict__ bo,  // (V,V)
    float* __restrict__ out)
{
    __shared__ __align__(16) float hcat[TBM][2 * VV];  // 16 KB
    __shared__ __align__(16) float gbuf[TBM][VV];      // 8 KB
    __shared__ __align__(16) float xbuf[TBM][VV];      // 8 KB

    const int t = threadIdx.x;
    const int bl = t >> 7;
    const int quad = t & 127;
    const int b = blockIdx.x * TBM + bl;

    // stage hidden + combine chunk partials into retrieved
    {
        ((float4*)hcat[bl])[quad] = ((const float4*)(hidden + (size_t)b * VV))[quad];
        const float* mlb = ml + (size_t)b * NC * 2;
        const float m0 = mlb[0], l0 = mlb[1], m1 = mlb[2], l1 = mlb[3];
        const float m2 = mlb[4], l2 = mlb[5], m3 = mlb[6], l3 = mlb[7];
        const float ms = fmaxf(fmaxf(m0, m1), fmaxf(m2, m3));
        const float w0 = __expf(m0 - ms), w1 = __expf(m1 - ms);
        const float w2 = __expf(m2 - ms), w3 = __expf(m3 - ms);
        const float invd = 1.f / (w0 * l0 + w1 * l1 + w2 * l2 + w3 * l3);
        const float4* a0 = (const float4*)(accp + ((size_t)b * NC + 0) * VV);
        const float4* a1 = (const float4*)(accp + ((size_t)b * NC + 1) * VV);
        const float4* a2 = (const float4*)(accp + ((size_t)b * NC + 2) * VV);
        const float4* a3 = (const float4*)(accp + ((size_t)b * NC + 3) * VV);
        const float4 x0 = a0[quad], x1 = a1[quad], x2 = a2[quad], x3 = a3[quad];
        float4 r;
        r.x = (w0 * x0.x + w1 * x1.x + w2 * x2.x + w3 * x3.x) * invd;
        r.y = (w0 * x0.y + w1 * x1.y + w2 * x2.y + w3 * x3.y) * invd;
        r.z = (w0 * x0.z + w1 * x1.z + w2 * x2.z + w3 * x3.z) * invd;
        r.w = (w0 * x0.w + w1 * x1.w + w2 * x2.w + w3 * x3.w) * invd;
        ((float4*)hcat[bl])[VV / 4 + quad] = r;
    }
    __syncthreads();

    float4 acc;
    // layer 1: k over 2V
    {
        acc = ((const float4*)bg1)[quad];
        const float4* w4 = (const float4*)wt1;
        const float4* x4 = (const float4*)hcat[bl];
        #pragma unroll 2
        for (int k4 = 0; k4 < 2 * VV / 4; ++k4) {
            const float4 x = x4[k4];
            const float4 w0 = w4[(size_t)(4 * k4 + 0) * 128 + quad];
            const float4 w1 = w4[(size_t)(4 * k4 + 1) * 128 + quad];
            const float4 w2 = w4[(size_t)(4 * k4 + 2) * 128 + quad];
            const float4 w3 = w4[(size_t)(4 * k4 + 3) * 128 + quad];
            acc.x += x.x * w0.x + x.y * w1.x + x.z * w2.x + x.w * w3.x;
            acc.y += x.x * w0.y + x.y * w1.y + x.z * w2.y + x.w * w3.y;
            acc.z += x.x * w0.z + x.y * w1.z + x.z * w2.z + x.w * w3.z;
            acc.w += x.x * w0.w + x.y * w1.w + x.z * w2.w + x.w * w3.w;
        }
        float4 g;
        g.x = acc.x / (1.f + __expf(-acc.x));
        g.y = acc.y / (1.f + __expf(-acc.y));
        g.z = acc.z / (1.f + __expf(-acc.z));
        g.w = acc.w / (1.f + __expf(-acc.w));
        ((float4*)gbuf[bl])[quad] = g;
    }
    __syncthreads();
    // layer 2 + gating
    {
        acc = ((const float4*)bg2)[quad];
        const float4* w4 = (const float4*)wt2;
        const float4* x4 = (const float4*)gbuf[bl];
        #pragma unroll 2
        for (int k4 = 0; k4 < VV / 4; ++k4) {
            const float4 x = x4[k4];
            const float4 w0 = w4[(size_t)(4 * k4 + 0) * 128 + quad];
            const float4 w1 = w4[(size_t)(4 * k4 + 1) * 128 + quad];
            const float4 w2 = w4[(size_t)(4 * k4 + 2) * 128 + quad];
            const float4 w3 = w4[(size_t)(4 * k4 + 3) * 128 + quad];
            acc.x += x.x * w0.x + x.y * w1.x + x.z * w2.x + x.w * w3.x;
            acc.y += x.x * w0.y + x.y * w1.y + x.z * w2.y + x.w * w3.y;
            acc.z += x.x * w0.z + x.y * w1.z + x.z * w2.z + x.w * w3.z;
            acc.w += x.x * w0.w + x.y * w1.w + x.z * w2.w + x.w * w3.w;
        }
        const float4 h = ((const float4*)hcat[bl])[quad];
        const float4 r = ((const float4*)hcat[bl])[VV / 4 + quad];
        float4 xv;
        xv.x = h.x + r.x / (1.f + __expf(-acc.x));
        xv.y = h.y + r.y / (1.f + __expf(-acc.y));
        xv.z = h.z + r.z / (1.f + __expf(-acc.z));
        xv.w = h.w + r.w / (1.f + __expf(-acc.w));
        ((float4*)xbuf[bl])[quad] = xv;
    }
    __syncthreads();
    // layer 3
    {
        acc = ((const float4*)bo)[quad];
        const float4* w4 = (const float4*)wto;
        const float4* x4 = (const float4*)xbuf[bl];
        #pragma unroll 2
        for (int k4 = 0; k4 < VV / 4; ++k4) {
            const float4 x = x4[k4];
            const float4 w0 = w4[(size_t)(4 * k4 + 0) * 128 + quad];
            const float4 w1 = w4[(size_t)(4 * k4 + 1) * 128 + quad];
            const float4 w2 = w4[(size_t)(4 * k4 + 2) * 128 + quad];
            const float4 w3 = w4[(size_t)(4 * k4 + 3) * 128 + quad];
            acc.x += x.x * w0.x + x.y * w1.x + x.z * w2.x + x.w * w3.x;
            acc.y += x.x * w0.y + x.y * w1.y + x.z * w2.y + x.w * w3.y;
            acc.z += x.x * w0.z + x.y * w1.z + x.z * w2.z + x.w * w3.z;
            acc.w += x.x * w0.w + x.y * w1.w + x.z * w2.w + x.w * w3.w;
        }
        ((float4*)(out + (size_t)b * VV))[quad] = acc;
    }
}

extern "C" void kernel_launch(void* const* d_in, const int* in_sizes, int n_in,
                              void* d_out, int out_size, void* d_ws, size_t ws_size,
                              hipStream_t stream) {
    const float* keys    = (const float*)d_in[0];
    const float* values  = (const float*)d_in[1];
    const float* keyv    = (const float*)d_in[2];
    const float* valv    = (const float*)d_in[3];
    const float* hidden  = (const float*)d_in[4];
    const int*   wptr    = (const int*)d_in[5];
    const int*   filled  = (const int*)d_in[6];
    const float* Wq  = (const float*)d_in[7];
    const float* bq  = (const float*)d_in[8];
    const float* Wg1 = (const float*)d_in[9];
    const float* bg1 = (const float*)d_in[10];
    const float* Wg2 = (const float*)d_in[11];
    const float* bg2 = (const float*)d_in[12];
    const float* Wo  = (const float*)d_in[13];
    const float* bo  = (const float*)d_in[14];
    float* out = (float*)d_out;

    // workspace layout (floats)
    float* ws   = (float*)d_ws;
    float* q    = ws;                                   // B*K      = 65536
    float* ml   = q + (size_t)BB * KK;                  // B*NC*2   = 4096
    float* accp = ml + (size_t)BB * NC * 2;             // B*NC*V   = 1048576
    float* wt1  = accp + (size_t)BB * NC * VV;          // 2V*V     = 524288
    float* wt2  = wt1 + (size_t)2 * VV * VV;            // V*V      = 262144
    float* wto  = wt2 + (size_t)VV * VV;                // V*V      = 262144

    q_kernel<<<BB, 128, 0, stream>>>(hidden, Wq, bq, q);
    transpose3_kernel<<<1024, 256, 0, stream>>>(Wg1, Wg2, Wo, wt1, wt2, wto);
    // MEASUREMENT: attn_chunk launched TWICE (deterministic, idempotent).
    // attn duration A = dur_us(this round) - 326.4 (R3 baseline).
    attn_chunk_kernel<<<BB * NC, 256, 0, stream>>>(keys, values, keyv, valv, q,
                                                   wptr, filled, ml, accp);
    attn_chunk_kernel<<<BB * NC, 256, 0, stream>>>(keys, values, keyv, valv, q,
                                                   wptr, filled, ml, accp);
    mlp_kernel<<<BB / TBM, 512, 0, stream>>>(hidden, ml, accp,
                                             wt1, bg1, wt2, bg2, wto, bo, out);
}

// Round 6
// 231.402 us; speedup vs baseline: 2.0273x; 2.0273x over previous
//
#include <hip/hip_runtime.h>
#include <math.h>

#define BB 512
#define SS 1024
#define KK 128
#define VV 512
#define NC 4      // s-chunks per batch
#define CH 256    // rows per chunk

static constexpr float INV_SCALE = 0.088388347648318447f; // 1/sqrt(128)

// ---------------- query kernel: q[b,k] = hidden[b] . Wq[k] + bq[k] -----------
__global__ __launch_bounds__(128) void q_kernel(
    const float* __restrict__ hidden, const float* __restrict__ Wq,
    const float* __restrict__ bq, float* __restrict__ qout)
{
    __shared__ __align__(16) float hid[VV];
    const int b = blockIdx.x, t = threadIdx.x;
    ((float4*)hid)[t] = ((const float4*)(hidden + (size_t)b * VV))[t];
    __syncthreads();
    const float4* w4 = (const float4*)(Wq + (size_t)t * VV);
    const float4* h4 = (const float4*)hid;
    float acc = 0.f;
    #pragma unroll 8
    for (int v = 0; v < VV / 4; ++v) {
        float4 a = w4[v], h = h4[v];
        acc += a.x * h.x + a.y * h.y + a.z * h.z + a.w * h.w;
    }
    qout[(size_t)b * KK + t] = acc + bq[t];
}

// ---------------- transpose the three MLP weights into ws --------------------
__global__ __launch_bounds__(256) void transpose3_kernel(
    const float* __restrict__ Wg1, const float* __restrict__ Wg2,
    const float* __restrict__ Wo,
    float* __restrict__ wt1, float* __restrict__ wt2, float* __restrict__ wto)
{
    __shared__ float tile[32][33];
    const int idx = blockIdx.x;
    const float* in; float* out; int C, R, tid;
    if (idx < 512)      { in = Wg1; out = wt1; R = 512; C = 1024; tid = idx; }
    else if (idx < 768) { in = Wg2; out = wt2; R = 512; C = 512;  tid = idx - 512; }
    else                { in = Wo;  out = wto; R = 512; C = 512;  tid = idx - 768; }
    const int tiles_x = C >> 5;
    const int bx = (tid % tiles_x) << 5;
    const int by = (tid / tiles_x) << 5;
    const int tx = threadIdx.x & 31, ty0 = threadIdx.x >> 5;
    #pragma unroll
    for (int i = 0; i < 32; i += 8)
        tile[ty0 + i][tx] = in[(size_t)(by + ty0 + i) * C + bx + tx];
    __syncthreads();
    #pragma unroll
    for (int i = 0; i < 32; i += 8)
        out[(size_t)(bx + ty0 + i) * R + by + tx] = tile[tx][ty0 + i];
}

// ---------------- attention chunk (unchanged from R3) ------------------------
__global__ __launch_bounds__(256) void attn_chunk_kernel(
    const float* __restrict__ keys, const float* __restrict__ values,
    const float* __restrict__ keyv, const float* __restrict__ valv,
    const float* __restrict__ q,
    const int* __restrict__ write_ptr, const int* __restrict__ filled,
    float* __restrict__ ml, float* __restrict__ accp)
{
    __shared__ __align__(16) float qs[KK];
    __shared__ __align__(16) float p[CH];
    __shared__ __align__(16) float red[4];
    __shared__ __align__(16) float4 pvp[VV / 4];

    const int bc = blockIdx.x;
    const int b = bc >> 2;
    const int c = bc & 3;
    const int t = threadIdx.x;
    const int wave = t >> 6, lane = t & 63;

    int f = filled[b] + 1; if (f > SS) f = SS;
    const int sbeg = c * CH;
    int n = f - sbeg; if (n > CH) n = CH;

    float* mlrow = ml + ((size_t)b * NC + c) * 2;
    float* arow  = accp + ((size_t)b * NC + c) * VV;

    if (n <= 0) {
        if (t == 0) { mlrow[0] = -INFINITY; mlrow[1] = 0.f; }
        if (t < VV / 4) ((float4*)arow)[t] = make_float4(0.f, 0.f, 0.f, 0.f);
        return;
    }

    if (t < KK / 4) ((float4*)qs)[t] = ((const float4*)(q + (size_t)b * KK))[t];
    __syncthreads();

    const int sub = lane & 31, rsel = lane >> 5;
    const int srow = wave * 2 + rsel;  // 0..7
    const float4 q4 = ((const float4*)qs)[sub];
    const float* kb = keys + ((size_t)b * SS + sbeg) * KK;
    const float* kw = keyv + (size_t)b * KK;
    const int wpl = write_ptr[b] - sbeg;

    const int nmain = n & ~31;
    for (int s0 = 0; s0 < nmain; s0 += 32) {
        float4 kv[4];
        #pragma unroll
        for (int u = 0; u < 4; ++u) {
            const int s = s0 + u * 8 + srow;
            const float* kr = (s == wpl) ? kw : (kb + (size_t)s * KK);
            kv[u] = ((const float4*)kr)[sub];
        }
        #pragma unroll
        for (int u = 0; u < 4; ++u) {
            float prt = kv[u].x * q4.x + kv[u].y * q4.y
                      + kv[u].z * q4.z + kv[u].w * q4.w;
            prt += __shfl_xor(prt, 16);
            prt += __shfl_xor(prt, 8);
            prt += __shfl_xor(prt, 4);
            prt += __shfl_xor(prt, 2);
            prt += __shfl_xor(prt, 1);
            if (sub == 0) p[s0 + u * 8 + srow] = prt * INV_SCALE;
        }
    }
    for (int s = nmain + srow; s < n; s += 8) {
        const float* kr = (s == wpl) ? kw : (kb + (size_t)s * KK);
        const float4 kv = ((const float4*)kr)[sub];
        float prt = kv.x * q4.x + kv.y * q4.y + kv.z * q4.z + kv.w * q4.w;
        prt += __shfl_xor(prt, 16);
        prt += __shfl_xor(prt, 8);
        prt += __shfl_xor(prt, 4);
        prt += __shfl_xor(prt, 2);
        prt += __shfl_xor(prt, 1);
        if (sub == 0) p[s] = prt * INV_SCALE;
    }
    __syncthreads();

    float lmax = -INFINITY;
    for (int i = t; i < n; i += 256) lmax = fmaxf(lmax, p[i]);
    lmax = fmaxf(lmax, __shfl_xor(lmax, 32));
    lmax = fmaxf(lmax, __shfl_xor(lmax, 16));
    lmax = fmaxf(lmax, __shfl_xor(lmax, 8));
    lmax = fmaxf(lmax, __shfl_xor(lmax, 4));
    lmax = fmaxf(lmax, __shfl_xor(lmax, 2));
    lmax = fmaxf(lmax, __shfl_xor(lmax, 1));
    if (lane == 0) red[wave] = lmax;
    __syncthreads();
    const float m = fmaxf(fmaxf(red[0], red[1]), fmaxf(red[2], red[3]));
    float lsum = 0.f;
    for (int i = t; i < n; i += 256) {
        const float e = __expf(p[i] - m);
        p[i] = e;
        lsum += e;
    }
    lsum += __shfl_xor(lsum, 32);
    lsum += __shfl_xor(lsum, 16);
    lsum += __shfl_xor(lsum, 8);
    lsum += __shfl_xor(lsum, 4);
    lsum += __shfl_xor(lsum, 2);
    lsum += __shfl_xor(lsum, 1);
    __syncthreads();
    if (lane == 0) red[wave] = lsum;
    __syncthreads();
    const float l = red[0] + red[1] + red[2] + red[3];

    const int col4 = t & 127, stream = t >> 7;
    const float4* vb = (const float4*)(values + ((size_t)b * SS + sbeg) * VV);
    const float4* vw = (const float4*)(valv + (size_t)b * VV);
    float4 acc = make_float4(0.f, 0.f, 0.f, 0.f);
    const int nm2 = n & ~15;
    for (int s0 = 0; s0 < nm2; s0 += 16) {
        float4 v[8]; float ps[8];
        #pragma unroll
        for (int u = 0; u < 8; ++u) {
            const int s = s0 + u * 2 + stream;
            const float4* vr = (s == wpl) ? vw : (vb + (size_t)s * (VV / 4));
            v[u] = vr[col4];
            ps[u] = p[s];
        }
        #pragma unroll
        for (int u = 0; u < 8; ++u) {
            acc.x += ps[u] * v[u].x;
            acc.y += ps[u] * v[u].y;
            acc.z += ps[u] * v[u].z;
            acc.w += ps[u] * v[u].w;
        }
    }
    for (int s = nm2 + stream; s < n; s += 2) {
        const float4* vr = (s == wpl) ? vw : (vb + (size_t)s * (VV / 4));
        const float4 v = vr[col4];
        const float psv = p[s];
        acc.x += psv * v.x;
        acc.y += psv * v.y;
        acc.z += psv * v.z;
        acc.w += psv * v.w;
    }
    if (stream == 1) pvp[col4] = acc;
    __syncthreads();
    if (stream == 0) {
        const float4 o = pvp[col4];
        ((float4*)arow)[col4] = make_float4(acc.x + o.x, acc.y + o.y,
                                            acc.z + o.z, acc.w + o.w);
    }
    if (t == 0) { mlrow[0] = m; mlrow[1] = l; }
}

// ---------------- combine chunk partials -> hcat = [hidden | retrieved] ------
__global__ __launch_bounds__(128) void combine_kernel(
    const float* __restrict__ hidden, const float* __restrict__ ml,
    const float* __restrict__ accp, float* __restrict__ hcat)
{
    const int b = blockIdx.x, t = threadIdx.x;
    const float* mlb = ml + (size_t)b * NC * 2;
    const float m0 = mlb[0], l0 = mlb[1], m1 = mlb[2], l1 = mlb[3];
    const float m2 = mlb[4], l2 = mlb[5], m3 = mlb[6], l3 = mlb[7];
    const float ms = fmaxf(fmaxf(m0, m1), fmaxf(m2, m3));
    const float w0 = __expf(m0 - ms), w1 = __expf(m1 - ms);
    const float w2 = __expf(m2 - ms), w3 = __expf(m3 - ms);
    const float invd = 1.f / (w0 * l0 + w1 * l1 + w2 * l2 + w3 * l3);
    const float4 x0 = ((const float4*)(accp + ((size_t)b * NC + 0) * VV))[t];
    const float4 x1 = ((const float4*)(accp + ((size_t)b * NC + 1) * VV))[t];
    const float4 x2 = ((const float4*)(accp + ((size_t)b * NC + 2) * VV))[t];
    const float4 x3 = ((const float4*)(accp + ((size_t)b * NC + 3) * VV))[t];
    float4 r;
    r.x = (w0 * x0.x + w1 * x1.x + w2 * x2.x + w3 * x3.x) * invd;
    r.y = (w0 * x0.y + w1 * x1.y + w2 * x2.y + w3 * x3.y) * invd;
    r.z = (w0 * x0.z + w1 * x1.z + w2 * x2.z + w3 * x3.z) * invd;
    r.w = (w0 * x0.w + w1 * x1.w + w2 * x2.w + w3 * x3.w) * invd;
    float4* hc = (float4*)(hcat + (size_t)b * 2 * VV);
    hc[t] = ((const float4*)(hidden + (size_t)b * VV))[t];
    hc[VV / 4 + t] = r;
}

// ---------------- K-split tiled fp32 GEMM: part[ks] = A[:,kseg] @ B[kseg,:] --
// C is 512x512. Tile 64x64, 256 threads, 4x4 micro-tile, BK=16 LDS-staged.
// grid = 8 (mt) x 8 (nt) x 4 (ks) = 256 blocks.
__global__ __launch_bounds__(256) void gemm_ks_kernel(
    const float* __restrict__ A, int K, const float* __restrict__ B,
    float* __restrict__ part)
{
    __shared__ __align__(16) float As[16][68];
    __shared__ __align__(16) float Bs[16][68];
    const int bx = blockIdx.x;
    const int mt = bx & 7, nt = (bx >> 3) & 7, ks = bx >> 6;
    const int kseg = K >> 2;
    const int kbeg = ks * kseg, kend = kbeg + kseg;
    const int t = threadIdx.x;
    const int tx = t & 15, ty = t >> 4;
    const int m0 = mt << 6, n0 = nt << 6;
    const int ra = t >> 2, ca = (t & 3) << 2;   // A-stage: row, k-col4
    const int rb = t >> 4, jb = (t & 15) << 2;  // B-stage: k-row, n-col4
    float4 a0 = {0,0,0,0}, a1 = {0,0,0,0}, a2 = {0,0,0,0}, a3 = {0,0,0,0};

    for (int k0 = kbeg; k0 < kend; k0 += 16) {
        const float4 av = *(const float4*)(A + (size_t)(m0 + ra) * K + k0 + ca);
        const float4 bv = *(const float4*)(B + (size_t)(k0 + rb) * VV + n0 + jb);
        As[ca + 0][ra] = av.x;
        As[ca + 1][ra] = av.y;
        As[ca + 2][ra] = av.z;
        As[ca + 3][ra] = av.w;
        *(float4*)&Bs[rb][jb] = bv;
        __syncthreads();
        #pragma unroll
        for (int k = 0; k < 16; ++k) {
            const float4 a = *(const float4*)&As[k][ty << 2];
            const float4 b = *(const float4*)&Bs[k][tx << 2];
            a0.x += a.x * b.x; a0.y += a.x * b.y; a0.z += a.x * b.z; a0.w += a.x * b.w;
            a1.x += a.y * b.x; a1.y += a.y * b.y; a1.z += a.y * b.z; a1.w += a.y * b.w;
            a2.x += a.z * b.x; a2.y += a.z * b.y; a2.z += a.z * b.z; a2.w += a.z * b.w;
            a3.x += a.w * b.x; a3.y += a.w * b.y; a3.z += a.w * b.z; a3.w += a.w * b.w;
        }
        __syncthreads();
    }
    float* pp = part + ((size_t)(ks * 512 + m0 + (ty << 2))) * 512 + n0 + (tx << 2);
    *(float4*)(pp + 0 * 512) = a0;
    *(float4*)(pp + 1 * 512) = a1;
    *(float4*)(pp + 2 * 512) = a2;
    *(float4*)(pp + 3 * 512) = a3;
}

// ---------------- reduce kernels: sum K-split partials + epilogue ------------
__global__ __launch_bounds__(128) void reduce_silu_kernel(
    const float* __restrict__ part, const float* __restrict__ bg1,
    float* __restrict__ G)
{
    const int b = blockIdx.x, t = threadIdx.x;
    const size_t o = (size_t)b * (VV / 4) + t;
    const size_t st = (size_t)512 * (VV / 4);
    const float4* p4 = (const float4*)part;
    const float4 s0 = p4[o], s1 = p4[o + st], s2 = p4[o + 2 * st], s3 = p4[o + 3 * st];
    const float4 bb = ((const float4*)bg1)[t];
    float4 s;
    s.x = s0.x + s1.x + s2.x + s3.x + bb.x;
    s.y = s0.y + s1.y + s2.y + s3.y + bb.y;
    s.z = s0.z + s1.z + s2.z + s3.z + bb.z;
    s.w = s0.w + s1.w + s2.w + s3.w + bb.w;
    float4 g;
    g.x = s.x / (1.f + __expf(-s.x));
    g.y = s.y / (1.f + __expf(-s.y));
    g.z = s.z / (1.f + __expf(-s.z));
    g.w = s.w / (1.f + __expf(-s.w));
    ((float4*)G)[o] = g;
}

__global__ __launch_bounds__(128) void reduce_gate_kernel(
    const float* __restrict__ part, const float* __restrict__ bg2,
    const float* __restrict__ hcat, float* __restrict__ X)
{
    const int b = blockIdx.x, t = threadIdx.x;
    const size_t o = (size_t)b * (VV / 4) + t;
    const size_t st = (size_t)512 * (VV / 4);
    const float4* p4 = (const float4*)part;
    const float4 s0 = p4[o], s1 = p4[o + st], s2 = p4[o + 2 * st], s3 = p4[o + 3 * st];
    const float4 bb = ((const float4*)bg2)[t];
    float4 s;
    s.x = s0.x + s1.x + s2.x + s3.x + bb.x;
    s.y = s0.y + s1.y + s2.y + s3.y + bb.y;
    s.z = s0.z + s1.z + s2.z + s3.z + bb.z;
    s.w = s0.w + s1.w + s2.w + s3.w + bb.w;
    const float4* hc = (const float4*)(hcat + (size_t)b * 2 * VV);
    const float4 h = hc[t];
    const float4 r = hc[VV / 4 + t];
    float4 x;
    x.x = h.x + r.x / (1.f + __expf(-s.x));
    x.y = h.y + r.y / (1.f + __expf(-s.y));
    x.z = h.z + r.z / (1.f + __expf(-s.z));
    x.w = h.w + r.w / (1.f + __expf(-s.w));
    ((float4*)X)[o] = x;
}

__global__ __launch_bounds__(128) void reduce_bias_kernel(
    const float* __restrict__ part, const float* __restrict__ bo,
    float* __restrict__ out)
{
    const int b = blockIdx.x, t = threadIdx.x;
    const size_t o = (size_t)b * (VV / 4) + t;
    const size_t st = (size_t)512 * (VV / 4);
    const float4* p4 = (const float4*)part;
    const float4 s0 = p4[o], s1 = p4[o + st], s2 = p4[o + 2 * st], s3 = p4[o + 3 * st];
    const float4 bb = ((const float4*)bo)[t];
    float4 s;
    s.x = s0.x + s1.x + s2.x + s3.x + bb.x;
    s.y = s0.y + s1.y + s2.y + s3.y + bb.y;
    s.z = s0.z + s1.z + s2.z + s3.z + bb.z;
    s.w = s0.w + s1.w + s2.w + s3.w + bb.w;
    ((float4*)out)[o] = s;
}

extern "C" void kernel_launch(void* const* d_in, const int* in_sizes, int n_in,
                              void* d_out, int out_size, void* d_ws, size_t ws_size,
                              hipStream_t stream) {
    const float* keys    = (const float*)d_in[0];
    const float* values  = (const float*)d_in[1];
    const float* keyv    = (const float*)d_in[2];
    const float* valv    = (const float*)d_in[3];
    const float* hidden  = (const float*)d_in[4];
    const int*   wptr    = (const int*)d_in[5];
    const int*   filled  = (const int*)d_in[6];
    const float* Wq  = (const float*)d_in[7];
    const float* bq  = (const float*)d_in[8];
    const float* Wg1 = (const float*)d_in[9];
    const float* bg1 = (const float*)d_in[10];
    const float* Wg2 = (const float*)d_in[11];
    const float* bg2 = (const float*)d_in[12];
    const float* Wo  = (const float*)d_in[13];
    const float* bo  = (const float*)d_in[14];
    float* out = (float*)d_out;

    // workspace layout (floats)
    float* ws   = (float*)d_ws;
    float* q    = ws;                                   // 65536
    float* ml   = q + (size_t)BB * KK;                  // 4096
    float* accp = ml + (size_t)BB * NC * 2;             // 1048576
    float* wt1  = accp + (size_t)BB * NC * VV;          // 524288
    float* wt2  = wt1 + (size_t)2 * VV * VV;            // 262144
    float* wto  = wt2 + (size_t)VV * VV;                // 262144
    float* hcat = wto + (size_t)VV * VV;                // 524288
    float* G    = hcat + (size_t)BB * 2 * VV;           // 262144
    float* X    = G + (size_t)BB * VV;                  // 262144
    float* part = X + (size_t)BB * VV;                  // 1048576

    q_kernel<<<BB, 128, 0, stream>>>(hidden, Wq, bq, q);
    transpose3_kernel<<<1024, 256, 0, stream>>>(Wg1, Wg2, Wo, wt1, wt2, wto);
    attn_chunk_kernel<<<BB * NC, 256, 0, stream>>>(keys, values, keyv, valv, q,
                                                   wptr, filled, ml, accp);
    combine_kernel<<<BB, 128, 0, stream>>>(hidden, ml, accp, hcat);

    gemm_ks_kernel<<<256, 256, 0, stream>>>(hcat, 2 * VV, wt1, part);
    reduce_silu_kernel<<<BB, 128, 0, stream>>>(part, bg1, G);

    gemm_ks_kernel<<<256, 256, 0, stream>>>(G, VV, wt2, part);
    reduce_gate_kernel<<<BB, 128, 0, stream>>>(part, bg2, hcat, X);

    gemm_ks_kernel<<<256, 256, 0, stream>>>(X, VV, wto, part);
    reduce_bias_kernel<<<BB, 128, 0, stream>>>(part, bo, out);
}